// Round 15
// baseline (108.865 us; speedup 1.0000x reference)
//
#include <hip/hip_runtime.h>
#include <hip/hip_bf16.h>
#include <stdint.h>

#define BTOT 4096
#define RR   64
#define DIMD 128
#define WROW 40   /* wave-buffer row stride in shorts (80 B): bank-friendly */

typedef short s16x8 __attribute__((ext_vector_type(8)));
typedef float f32x4 __attribute__((ext_vector_type(4)));

__device__ __forceinline__ unsigned short f2bf(float x) {
  __hip_bfloat16 h = __float2bfloat16(x);
  return __builtin_bit_cast(unsigned short, h);
}
__device__ __forceinline__ float bf2f(unsigned short u) {
  unsigned int v = ((unsigned int)u) << 16;
  return __builtin_bit_cast(float, v);
}

// ---------------------------------------------------------------------------
// Pre-kernel: qproj[b,k] = sum_d query_r[b,d]*W1[k,128+d] + b1[k]  (fp32),
// offset_emb passthrough, and blocks 0/1 emit XOR-swizzled bf16 copies of
// W1a / W2 into ws.  Swizzle: element (k,d) at k*128 + (d ^ ((k&7)<<3)).
// ---------------------------------------------------------------------------
__global__ __launch_bounds__(256) void prep_kernel(
    const float* __restrict__ W1, const float* __restrict__ b1,
    const float* __restrict__ query_r, const float* __restrict__ W2,
    const float* __restrict__ offset_emb,
    float* __restrict__ qproj, unsigned short* __restrict__ w1a_swz,
    unsigned short* __restrict__ w2_swz, float* __restrict__ out)
{
  __shared__ float w1b[128 * 132];   // +4 pad
  __shared__ float qrs[256];
  const int tid = threadIdx.x;

  { // offset_emb passthrough (1 float4 per thread; 512 blocks cover 4096x128)
    const size_t ob = (size_t)blockIdx.x * 8 * DIMD + (size_t)tid * 4;
    *reinterpret_cast<float4*>(out + (size_t)BTOT * DIMD + ob) =
        *reinterpret_cast<const float4*>(offset_emb + ob);
  }
  { // stage W1b fp32 into padded LDS
    const int k = tid >> 1, d0 = (tid & 1) * 64;
    const float* src = W1 + k * 256 + 128 + d0;
    float* dst = &w1b[k * 132 + d0];
    #pragma unroll
    for (int i = 0; i < 64; i += 4)
      *reinterpret_cast<float4*>(dst + i) = *reinterpret_cast<const float4*>(src + i);
  }
  if (blockIdx.x < 2) { // swizzled bf16 weights
    const float* Wsrc = (blockIdx.x == 0) ? W1 : W2;
    unsigned short* dstw = (blockIdx.x == 0) ? w1a_swz : w2_swz;
    const int stride = (blockIdx.x == 0) ? 256 : 128;
    for (int i = tid; i < 128 * 128; i += 256) {
      const int k = i >> 7, d = i & 127;
      dstw[k * 128 + (d ^ ((k & 7) << 3))] = f2bf(Wsrc[k * stride + d]);
    }
  }
  __syncthreads();

  const int b0 = blockIdx.x * 8;
  const int k = tid & 127, bh = tid >> 7;
  for (int p = 0; p < 4; ++p) {
    const int b = b0 + p * 2;
    qrs[tid] = query_r[(size_t)(b + bh) * DIMD + k];
    __syncthreads();
    float acc = b1[k];
    const float* qq = &qrs[bh * 128];
    const float* wr = &w1b[k * 132];
    #pragma unroll
    for (int d = 0; d < 128; d += 4) {
      float4 wv = *reinterpret_cast<const float4*>(wr + d);
      float4 qv = *reinterpret_cast<const float4*>(qq + d);
      acc = fmaf(wv.x, qv.x, acc); acc = fmaf(wv.y, qv.y, acc);
      acc = fmaf(wv.z, qv.z, acc); acc = fmaf(wv.w, qv.w, acc);
    }
    qproj[(size_t)(b + bh) * DIMD + k] = acc;
    __syncthreads();
  }
}

// ---------------------------------------------------------------------------
// Main kernel: R14 byte-for-byte EXCEPT every
//   asm volatile("s_waitcnt lgkmcnt(0)" ::: "memory")
// is replaced by  __builtin_amdgcn_sched_barrier(0).
// Mechanism: the memory-clobber asm forced the backend to conservatively
// drain VMCNT at every phase boundary (a clobber may touch any memory ->
// outstanding global loads must complete). That is why R14's prefetch was a
// no-op (loads drained at the same quarter's fence) and why R11's fence
// removal raised delivered BW 1.55->2.22 TB/s. sched_barrier(0) keeps the
// phase structure pinned (no hoisting -> no R13 spill / stream reorder,
// FETCH stays ~200 MB) but emits NO waitcnt: global loads stay in flight
// across phases, LDS ordering falls to the compiler's precise lgkmcnt(N)
// insertion on may-alias LDS accesses (correct in R11/R12/R13, all passed).
// Depth-1 quarter prefetch (24 VGPR) now actually overlaps HBM latency with
// the MFMA+DS phases. LDS = 64 KB weights + 8 x 1.25 KB = 74 KB.
// ---------------------------------------------------------------------------
__global__ __launch_bounds__(512) void main_kernel(
    const float* __restrict__ query_emb,
    const float* __restrict__ refer_embs, const float* __restrict__ refer_r,
    const float* __restrict__ start_embs, const float* __restrict__ b2,
    const float* __restrict__ qproj, const unsigned short* __restrict__ w1a_swz,
    const unsigned short* __restrict__ w2_swz, float* __restrict__ out)
{
  __shared__ unsigned short lds_w1a[128 * 128];   // 32 KB, swizzled
  __shared__ unsigned short lds_w2[128 * 128];    // 32 KB, swizzled
  __shared__ unsigned short wbuf[8][16 * WROW];   // 1.25 KB per wave

  const int tid  = threadIdx.x;
  const int wave = tid >> 6;
  const int lane = tid & 63;
  const int g    = lane >> 4;   // k-group
  const int c    = lane & 15;   // row/col-in-tile

  { // stage swizzled weights (linear uint4 copy; swizzle pre-applied in ws)
    const uint4* s1 = reinterpret_cast<const uint4*>(w1a_swz);
    const uint4* s2 = reinterpret_cast<const uint4*>(w2_swz);
    uint4* d1 = reinterpret_cast<uint4*>(lds_w1a);
    uint4* d2 = reinterpret_cast<uint4*>(lds_w2);
    #pragma unroll
    for (int i = 0; i < 4; ++i) {
      d1[tid + 512 * i] = s1[tid + 512 * i];
      d2[tid + 512 * i] = s2[tid + 512 * i];
    }
  }
  __syncthreads();   // the ONLY barrier

  unsigned short* mybuf = &wbuf[wave][0];
  const int srl = lane >> 2;           // staging local row 0..15
  const int q   = lane & 3;            // staging quarter-of-row (8 floats)
  const int swc = (c & 7) << 3;        // weight swizzle for row nt*16+c
  const int rl4 = 4 * g;

  const int b = blockIdx.x * 8 + wave;  // this wave's b

  float qn[8], b2v[8], acc[8];
  #pragma unroll
  for (int nt = 0; nt < 8; ++nt) {
    qn[nt]  = qproj[(size_t)b * DIMD + nt * 16 + c];
    b2v[nt] = b2[nt * 16 + c];
    acc[nt] = 0.f;
  }

  // prefetch registers: exactly one quarter (6 x float4 = 24 VGPR)
  float4 Prv0, Prv1, Pev0, Pev1, Psv0, Psv1;

#define LOADQ(fq) do {                                                        \
    const int it_ = (fq) >> 2, Q_ = (fq) & 3;                                 \
    const size_t gb_ =                                                        \
        ((size_t)b * RR + it_ * 16 + srl) * DIMD + Q_ * 32 + q * 8;           \
    Prv0 = *reinterpret_cast<const float4*>(refer_r    + gb_);                \
    Prv1 = *reinterpret_cast<const float4*>(refer_r    + gb_ + 4);            \
    Pev0 = *reinterpret_cast<const float4*>(refer_embs + gb_);                \
    Pev1 = *reinterpret_cast<const float4*>(refer_embs + gb_ + 4);            \
    Psv0 = *reinterpret_cast<const float4*>(start_embs + gb_);                \
    Psv1 = *reinterpret_cast<const float4*>(start_embs + gb_ + 4);            \
  } while (0)

  LOADQ(0);   // prologue

  for (int it = 0; it < 4; ++it) {
    uint4 bp[4];          // packed bias (row layout), one per quarter
    f32x4 Ch[8];
    #pragma unroll
    for (int nt = 0; nt < 8; ++nt) Ch[nt] = (f32x4){qn[nt], qn[nt], qn[nt], qn[nt]};

    // ================= GEMM1 (four 32-wide d-quarters, pipelined) =========
    #pragma unroll
    for (int Q = 0; Q < 4; ++Q) {
      { // consume prefetched quarter: stage refer_r (one uint4 per lane)
        union { unsigned short u[8]; uint4 v; } pk;
        pk.u[0] = f2bf(Prv0.x); pk.u[1] = f2bf(Prv0.y);
        pk.u[2] = f2bf(Prv0.z); pk.u[3] = f2bf(Prv0.w);
        pk.u[4] = f2bf(Prv1.x); pk.u[5] = f2bf(Prv1.y);
        pk.u[6] = f2bf(Prv1.z); pk.u[7] = f2bf(Prv1.w);
        *reinterpret_cast<uint4*>(&mybuf[srl * WROW + q * 8]) = pk.v;
      }
      { // bias quarter = ev - sv - rv, packed bf16 (row layout, in regs)
        union { unsigned short u[8]; uint4 v; } pk;
        pk.u[0] = f2bf(Pev0.x - Psv0.x - Prv0.x);
        pk.u[1] = f2bf(Pev0.y - Psv0.y - Prv0.y);
        pk.u[2] = f2bf(Pev0.z - Psv0.z - Prv0.z);
        pk.u[3] = f2bf(Pev0.w - Psv0.w - Prv0.w);
        pk.u[4] = f2bf(Pev1.x - Psv1.x - Prv1.x);
        pk.u[5] = f2bf(Pev1.y - Psv1.y - Prv1.y);
        pk.u[6] = f2bf(Pev1.z - Psv1.z - Prv1.z);
        pk.u[7] = f2bf(Pev1.w - Psv1.w - Prv1.w);
        bp[Q] = pk.v;
      }
      { // issue next quarter's loads; with no vmcnt-draining fences these
        // stay in flight across the MFMA+DS phases until first use
        const int fq = it * 4 + Q;
        if (fq + 1 < 16) { LOADQ(fq + 1); }
      }
      __builtin_amdgcn_sched_barrier(0);
      const s16x8 af = *reinterpret_cast<const s16x8*>(&mybuf[c * WROW + g * 8]);
      #pragma unroll
      for (int nt = 0; nt < 8; ++nt) {
        s16x8 wf = *reinterpret_cast<const s16x8*>(
            &lds_w1a[(nt * 16 + c) * DIMD + ((Q * 32 + g * 8) ^ swc)]);
        Ch[nt] = __builtin_amdgcn_mfma_f32_16x16x32_bf16(af, wf, Ch[nt], 0, 0, 0);
      }
      __builtin_amdgcn_sched_barrier(0);   // af read stays before restage
    }

    // ================= GEMM2 (four 32-wide k_hid-quarters) =================
    f32x4 Ca[8];
    #pragma unroll
    for (int nt = 0; nt < 8; ++nt) Ca[nt] = (f32x4){b2v[nt], b2v[nt], b2v[nt], b2v[nt]};
    #pragma unroll
    for (int Q = 0; Q < 4; ++Q) {
      // h quarter (relu, bf16) at C positions: cols 2Q..2Q+1 of the nt grid
      #pragma unroll
      for (int ntl = 0; ntl < 2; ++ntl)
        #pragma unroll
        for (int r = 0; r < 4; ++r)
          mybuf[(rl4 + r) * WROW + ntl * 16 + c] = f2bf(fmaxf(Ch[2 * Q + ntl][r], 0.f));
      __builtin_amdgcn_sched_barrier(0);
      const s16x8 hf = *reinterpret_cast<const s16x8*>(&mybuf[c * WROW + g * 8]);
      #pragma unroll
      for (int nt = 0; nt < 8; ++nt) {
        s16x8 wf = *reinterpret_cast<const s16x8*>(
            &lds_w2[(nt * 16 + c) * DIMD + ((Q * 32 + g * 8) ^ swc)]);
        Ca[nt] = __builtin_amdgcn_mfma_f32_16x16x32_bf16(hf, wf, Ca[nt], 0, 0, 0);
      }
      __builtin_amdgcn_sched_barrier(0);   // hf read stays before restage
    }

    // ================= bias dot + reduce (four quarters) =================
    #pragma unroll
    for (int Q = 0; Q < 4; ++Q) {
      *reinterpret_cast<uint4*>(&mybuf[srl * WROW + q * 8]) = bp[Q];
      __builtin_amdgcn_sched_barrier(0);
      #pragma unroll
      for (int ntl = 0; ntl < 2; ++ntl) {
        const int nt = 2 * Q + ntl;
        float s = 0.f;
        #pragma unroll
        for (int r = 0; r < 4; ++r) {
          const float bcv = bf2f(mybuf[(rl4 + r) * WROW + ntl * 16 + c]);
          s = fmaf(Ca[nt][r], bcv, s);
        }
        s += __shfl_xor(s, 16);
        s += __shfl_xor(s, 32);
        acc[nt] += s;
      }
      __builtin_amdgcn_sched_barrier(0);   // reads stay before restage
    }
  }
#undef LOADQ

  // ---- epilogue
  if (lane < 16) {
    #pragma unroll
    for (int nt = 0; nt < 8; ++nt)
      out[(size_t)b * DIMD + nt * 16 + c] =
          query_emb[(size_t)b * DIMD + nt * 16 + c] + acc[nt];
  }
}

extern "C" void kernel_launch(void* const* d_in, const int* in_sizes, int n_in,
                              void* d_out, int out_size, void* d_ws, size_t ws_size,
                              hipStream_t stream) {
  const float* query_emb  = (const float*)d_in[0];
  const float* offset_emb = (const float*)d_in[1];
  const float* refer_embs = (const float*)d_in[2];
  const float* query_r    = (const float*)d_in[3];
  const float* refer_r    = (const float*)d_in[4];
  const float* start_embs = (const float*)d_in[5];
  const float* W1 = (const float*)d_in[6];
  const float* b1 = (const float*)d_in[7];
  const float* W2 = (const float*)d_in[8];
  const float* b2 = (const float*)d_in[9];
  float* out = (float*)d_out;

  float* qproj = (float*)d_ws;                       // 4096*128 f32 = 2 MB
  unsigned short* w1a_swz =
      (unsigned short*)((char*)d_ws + (size_t)BTOT * DIMD * sizeof(float));
  unsigned short* w2_swz = w1a_swz + 128 * 128;      // +32 KB each

  hipLaunchKernelGGL(prep_kernel, dim3(512), dim3(256), 0, stream,
                     W1, b1, query_r, W2, offset_emb, qproj, w1a_swz, w2_swz, out);
  hipLaunchKernelGGL(main_kernel, dim3(512), dim3(512), 0, stream,
                     query_emb, refer_embs, refer_r, start_embs,
                     b2, qproj, w1a_swz, w2_swz, out);
}